// Round 1
// baseline (482.396 us; speedup 1.0000x reference)
//
#include <hip/hip_runtime.h>
#include <stdint.h>

// Problem: out[b,f,o] = sum_i x[b,f,i]*W[f,i,o] + bias[f,o]
// B=4096, F=64, DIN=256, DOUT=256, fp32 in/out, bf16 MFMA compute.
#define BATCH 4096
#define FEAT  64
#define DIN   256
#define DOUT  256

typedef __attribute__((ext_vector_type(8))) short  short8;   // bf16x8 MFMA operand (4 VGPRs)
typedef __attribute__((ext_vector_type(4))) float  float4v;  // MFMA acc
typedef __attribute__((ext_vector_type(4))) unsigned int uint4v;

// Pack two fp32 -> dword of two bf16 (round-half-up: +0x8000 then take hi16).
// v_perm_b32 merges hi halves: D = [hi.b3, hi.b2, lo.b3, lo.b2]
__device__ __forceinline__ unsigned int pack_bf16(float lo, float hi) {
    unsigned int ulo = __builtin_bit_cast(unsigned int, lo) + 0x8000u;
    unsigned int uhi = __builtin_bit_cast(unsigned int, hi) + 0x8000u;
    return __builtin_amdgcn_perm(uhi, ulo, 0x07060302u);
}

// LDS A-tile: 64 rows x (256 + 8 pad) bf16 = 33792 B. Row stride 264*2=528 B
// (16B aligned; 132 dwords == 4 mod 32 banks -> frag reads bank-uniform).
#define A_STRIDE 264

__global__ __launch_bounds__(256, 2)
void nlinear_kernel(const float* __restrict__ x,
                    const float* __restrict__ w,
                    const float* __restrict__ bias,
                    float* __restrict__ out) {
    __shared__ __align__(16) unsigned short Alds[64 * A_STRIDE];

    const int tid = threadIdx.x;
    const int f   = blockIdx.x & 63;   // 64 m-blocks of same f -> same XCD (64%8==0)
    const int mb  = blockIdx.x >> 6;
    const int b0  = mb * 64;

    // ---- Stage x[b0..b0+63][f][:] -> bf16 LDS (coalesced float4 pairs) ----
    {
        const float* xb = x + (size_t)(b0 * FEAT + f) * DIN;  // row stride FEAT*DIN
        #pragma unroll
        for (int i = 0; i < 8; ++i) {
            int chunk = tid + 256 * i;          // 2048 chunks of 8 floats
            int row   = chunk >> 5;             // 0..63
            int c8    = (chunk & 31) * 8;       // 0..248
            const float* g = xb + row * (FEAT * DIN) + c8;
            float4v a0 = *(const float4v*)g;
            float4v a1 = *(const float4v*)(g + 4);
            uint4v p;
            p.x = pack_bf16(a0.x, a0.y);
            p.y = pack_bf16(a0.z, a0.w);
            p.z = pack_bf16(a1.x, a1.y);
            p.w = pack_bf16(a1.z, a1.w);
            *(uint4v*)&Alds[row * A_STRIDE + c8] = p;
        }
    }
    __syncthreads();   // the only barrier

    const int lane = tid & 63;
    const int wv   = tid >> 6;      // wave 0..3 -> n-slice of 64 cols
    const int q    = lane >> 4;     // quad 0..3
    const int l16  = lane & 15;
    const int n0   = wv * 64;

    // ---- Accumulators initialized with bias (col-dependent only) ----
    float4v acc[4][4];   // [m-subtile][n-subtile]
    #pragma unroll
    for (int s = 0; s < 4; ++s) {
        float bv = bias[f * DOUT + n0 + s * 16 + l16];
        #pragma unroll
        for (int mi = 0; mi < 4; ++mi)
            acc[mi][s] = (float4v){bv, bv, bv, bv};
    }

    // B frag source: W[f][k][n]; per-lane base covers q*8 k-rows + l16 col.
    const float* wp = w + (size_t)f * (DIN * DOUT) + n0 + q * 8 * DOUT + l16;
    const unsigned short* albase = Alds + l16 * A_STRIDE + q * 8;

    #pragma unroll 2
    for (int it = 0; it < 8; ++it) {
        const int kb = it * 32;
        const float* wk = wp + kb * DOUT;

        // B fragments: 8 L2-resident dword loads each (4x64B segments/load),
        // k = kb + q*8 + j for col n0 + s*16 + l16
        short8 bfrag[4];
        #pragma unroll
        for (int s = 0; s < 4; ++s) {
            float v0 = wk[0 * DOUT + s * 16];
            float v1 = wk[1 * DOUT + s * 16];
            float v2 = wk[2 * DOUT + s * 16];
            float v3 = wk[3 * DOUT + s * 16];
            float v4 = wk[4 * DOUT + s * 16];
            float v5 = wk[5 * DOUT + s * 16];
            float v6 = wk[6 * DOUT + s * 16];
            float v7 = wk[7 * DOUT + s * 16];
            uint4v p;
            p.x = pack_bf16(v0, v1);
            p.y = pack_bf16(v2, v3);
            p.z = pack_bf16(v4, v5);
            p.w = pack_bf16(v6, v7);
            bfrag[s] = __builtin_bit_cast(short8, p);
        }

        // A fragments: one ds_read_b128 each (A[m=l16+mi*16][kb+q*8 .. +7])
        short8 afrag[4];
        #pragma unroll
        for (int mi = 0; mi < 4; ++mi)
            afrag[mi] = *(const short8*)(albase + mi * 16 * A_STRIDE + kb);

        #pragma unroll
        for (int mi = 0; mi < 4; ++mi)
            #pragma unroll
            for (int s = 0; s < 4; ++s)
                acc[mi][s] = __builtin_amdgcn_mfma_f32_16x16x32_bf16(
                    afrag[mi], bfrag[s], acc[mi][s], 0, 0, 0);
    }

    // ---- Epilogue: C/D layout col = l16 (+s*16), row = q*4 + r (+mi*16) ----
    float* ob = out + (size_t)(b0 * FEAT + f) * DOUT + n0;
    #pragma unroll
    for (int mi = 0; mi < 4; ++mi) {
        #pragma unroll
        for (int r = 0; r < 4; ++r) {
            int m = mi * 16 + q * 4 + r;
            float* orow = ob + m * (FEAT * DOUT);
            #pragma unroll
            for (int s = 0; s < 4; ++s)
                orow[s * 16 + l16] = acc[mi][s][r];
        }
    }
}

extern "C" void kernel_launch(void* const* d_in, const int* in_sizes, int n_in,
                              void* d_out, int out_size, void* d_ws, size_t ws_size,
                              hipStream_t stream) {
    const float* x    = (const float*)d_in[0];   // (4096, 64, 256) fp32
    const float* w    = (const float*)d_in[1];   // (64, 256, 256) fp32
    const float* bias = (const float*)d_in[2];   // (64, 256) fp32
    float* out = (float*)d_out;                  // (4096, 64, 256) fp32

    // grid = m_block*64 + f : 64 m-blocks per feature, 4096 blocks total
    nlinear_kernel<<<dim3(FEAT * (BATCH / 64)), dim3(256), 0, stream>>>(x, w, bias, out);
}